// Round 3
// baseline (5840.937 us; speedup 1.0000x reference)
//
#include <hip/hip_runtime.h>

typedef unsigned short u16;
typedef unsigned int   u32;
typedef unsigned long long u64;
typedef __attribute__((ext_vector_type(8)))  short  short8v;   // 8 x bf16 (as i16)
typedef __attribute__((ext_vector_type(4)))  float  f32x4;
typedef __attribute__((ext_vector_type(16))) float  f32x16;
typedef __attribute__((ext_vector_type(4)))  unsigned short ushort4v;
typedef __attribute__((ext_vector_type(4)))  u32 u32x4;

#define B_   32
#define T_   512
#define D_   1024
#define N4_  4096

// ---- workspace layout (bytes) ----
#define OFF_XN   0ull                 // xn bf16   [32*512*1024]      33554432
#define OFF_ZX   33554432ull          // Zx bf16   [512][32][4096]   134217728
#define OFF_KT   167772160ull         // kernel^T bf16 [4096][1024]    8388608  (first 128KB reused as h_last after GEMM)
#define OFF_RT   176160768ull         // recurrent^T bf16 [4096][1024] 8388608
#define OFF_HT   184549376ull         // tagged h: 2 x [32][512] u64 = 262144
// h_last fp32 [32][1024] aliases OFF_KT (kernel^T dead after gemm_xk)

__device__ inline u16 f2bf(float f) {
  union { float f; u32 u; } x; x.f = f;
  u32 r = x.u + 0x7FFFu + ((x.u >> 16) & 1u);   // RNE
  return (u16)(r >> 16);
}
__device__ inline float bf2f(u16 h) {
  union { u32 u; float f; } x; x.u = ((u32)h) << 16; return x.f;
}
__device__ inline float sigm(float x) { return 1.f / (1.f + __expf(-x)); }
__device__ inline float tanh_fast(float x) {
  float e = __expf(2.f * x);
  return 1.f - 2.f / (e + 1.f);
}

// ---------------- init: zero tagged-h buffers (tags=0 -> h[0]=0 ready) ----------------
__global__ __launch_bounds__(256) void init_kernel(u64* htag) {
  int i = blockIdx.x * 256 + threadIdx.x;
  if (i < 32768) htag[i] = 0ull;     // 2 * 32*512 u64
}

// ---------------- LN1: x fp32 -> xn bf16 ----------------
__global__ __launch_bounds__(256) void ln1_kernel(const float* __restrict__ x,
    const float* __restrict__ gam, const float* __restrict__ bet, u16* __restrict__ xn) {
  int row = blockIdx.x; int tid = threadIdx.x;
  const float* xr = x + (size_t)row * D_;
  float4 v = *(const float4*)(xr + tid * 4);
  float s  = v.x + v.y + v.z + v.w;
  float ss = v.x*v.x + v.y*v.y + v.z*v.z + v.w*v.w;
  #pragma unroll
  for (int o = 32; o > 0; o >>= 1) { s += __shfl_down(s, o); ss += __shfl_down(ss, o); }
  __shared__ float red[8];
  int w = tid >> 6, l = tid & 63;
  if (l == 0) { red[w] = s; red[4 + w] = ss; }
  __syncthreads();
  s  = red[0] + red[1] + red[2] + red[3];
  ss = red[4] + red[5] + red[6] + red[7];
  float mean = s * (1.f / D_);
  float var  = ss * (1.f / D_) - mean * mean;
  float rstd = rsqrtf(var + 1e-3f);
  float4 g = *(const float4*)(gam + tid * 4);
  float4 b = *(const float4*)(bet + tid * 4);
  ushort4v o4;
  o4.x = f2bf((v.x - mean) * rstd * g.x + b.x);
  o4.y = f2bf((v.y - mean) * rstd * g.y + b.y);
  o4.z = f2bf((v.z - mean) * rstd * g.z + b.z);
  o4.w = f2bf((v.w - mean) * rstd * g.w + b.w);
  *(ushort4v*)(xn + (size_t)row * D_ + tid * 4) = o4;
}

// ---------------- transpose [1024][4096] fp32 -> [4096][1024] bf16 ----------------
__global__ __launch_bounds__(256) void transpose_bf16(const float* __restrict__ W, u16* __restrict__ WT) {
  __shared__ float tile[32][33];
  int c0 = blockIdx.x * 32, r0 = blockIdx.y * 32;
  int tx = threadIdx.x, ty = threadIdx.y;
  #pragma unroll
  for (int i = ty; i < 32; i += 8)
    tile[i][tx] = W[(size_t)(r0 + i) * N4_ + c0 + tx];
  __syncthreads();
  #pragma unroll
  for (int i = ty; i < 32; i += 8)
    WT[(size_t)(c0 + i) * D_ + r0 + tx] = f2bf(tile[tx][i]);
}

// ---------------- GEMM: Zx = xn @ kernel + bias ----------------
__global__ __launch_bounds__(256) void gemm_xk(const u16* __restrict__ A, const u16* __restrict__ Bt,
    const float* __restrict__ bias, u16* __restrict__ Zx) {
  __shared__ u16 As[128 * 32];
  __shared__ u16 Bs[128 * 32];
  int tid = threadIdx.x;
  int bm = blockIdx.x >> 5, bn = blockIdx.x & 31;
  int w = tid >> 6, l = tid & 63;
  int srow = tid >> 2, sk = (tid & 3) * 8;        // staging: row j*64+srow, k = sk..sk+8
  const u16* Ag = A  + (size_t)(bm * 128 + srow) * D_ + sk;
  const u16* Bg = Bt + (size_t)(bn * 128 + srow) * D_ + sk;
  int sb0 = (srow * 64 + sk * 2)          ^ ((srow & 3) << 4);
  int sb1 = ((srow + 64) * 64 + sk * 2)   ^ ((srow & 3) << 4);
  int wm = w >> 1, wn = w & 1;
  int frow = l & 15, fko = (l >> 4) * 16;         // fragment k byte offset
  f32x4 acc[4][4];
  #pragma unroll
  for (int mi = 0; mi < 4; ++mi)
    #pragma unroll
    for (int ni = 0; ni < 4; ++ni)
      #pragma unroll
      for (int j = 0; j < 4; ++j) acc[mi][ni][j] = 0.f;

  short8v ap0 = *(const short8v*)(Ag);
  short8v ap1 = *(const short8v*)(Ag + 64 * (size_t)D_);
  short8v bp0 = *(const short8v*)(Bg);
  short8v bp1 = *(const short8v*)(Bg + 64 * (size_t)D_);

  for (int kt = 0; kt < 32; ++kt) {
    __syncthreads();
    *(short8v*)((char*)As + sb0) = ap0;
    *(short8v*)((char*)As + sb1) = ap1;
    *(short8v*)((char*)Bs + sb0) = bp0;
    *(short8v*)((char*)Bs + sb1) = bp1;
    __syncthreads();
    if (kt < 31) {
      ap0 = *(const short8v*)(Ag + (kt + 1) * 32);
      ap1 = *(const short8v*)(Ag + 64 * (size_t)D_ + (kt + 1) * 32);
      bp0 = *(const short8v*)(Bg + (kt + 1) * 32);
      bp1 = *(const short8v*)(Bg + 64 * (size_t)D_ + (kt + 1) * 32);
    }
    short8v af[4], bfr[4];
    #pragma unroll
    for (int mi = 0; mi < 4; ++mi) {
      int r = wm * 64 + mi * 16 + frow;
      af[mi] = *(const short8v*)((char*)As + ((r * 64 + fko) ^ ((r & 3) << 4)));
    }
    #pragma unroll
    for (int ni = 0; ni < 4; ++ni) {
      int r = wn * 64 + ni * 16 + frow;
      bfr[ni] = *(const short8v*)((char*)Bs + ((r * 64 + fko) ^ ((r & 3) << 4)));
    }
    #pragma unroll
    for (int mi = 0; mi < 4; ++mi)
      #pragma unroll
      for (int ni = 0; ni < 4; ++ni)
        acc[mi][ni] = __builtin_amdgcn_mfma_f32_16x16x32_bf16(af[mi], bfr[ni], acc[mi][ni], 0, 0, 0);
  }
  // epilogue: +bias, bf16, remap rows to [t][b]
  #pragma unroll
  for (int mi = 0; mi < 4; ++mi) {
    #pragma unroll
    for (int ni = 0; ni < 4; ++ni) {
      int col = bn * 128 + wn * 64 + ni * 16 + (l & 15);
      float bv = bias[col];
      #pragma unroll
      for (int j = 0; j < 4; ++j) {
        int row = bm * 128 + wm * 64 + mi * 16 + (l >> 4) * 4 + j;
        int zrow = (row & 511) * 32 + (row >> 9);
        Zx[(size_t)zrow * N4_ + col] = f2bf(acc[mi][ni][j] + bv);
      }
    }
  }
}

// ---------------- persistent LSTM scan ----------------
// 32 WGs x 512 thr. WG wg owns units [wg*32, wg*32+32). 8 waves = 2 col-halves x 4 K-splits.
// Cross-WG h exchange: SELF-TAGGED u64 words (tag<<32 | 2xbf16), agent-scope relaxed,
// write-through. Consumers poll the data directly -> one global latency per step.
// No flags, no fences, no end-of-step barrier (poll subsumes it).
__global__ __launch_bounds__(512, 2) void lstm_scan(const u16* __restrict__ Zx,
    const u16* __restrict__ RT, u64* htag, float* h_last) {
  __shared__ u16   h_lds[B_ * D_];           // 64 KB, XOR-swizzled rows
  __shared__ float z_lds[128 * 129];         // 66 KB: [ks*32+row][stride 129]
  __shared__ float c_lds[B_ * 32];           // 4 KB:  [row][u]
  int tid = threadIdx.x;
  int wg = blockIdx.x;
  int w = tid >> 6, l = tid & 63;
  int cb = w & 1, ks = w >> 1;               // col-half (gates 2cb,2cb+1), k-range ks*256..+256
  c_lds[tid] = 0.f; c_lds[tid + 512] = 0.f;

  // preload B fragments (R^T) into registers: 2 gates x 16 k-steps
  int bcol = l & 31;                         // unit within wg
  int bk = ks * 256 + (l >> 5) * 8;          // k base for this lane
  short8v b0[16], b1[16];
  {
    const u16* R0 = RT + (size_t)((cb * 2 + 0) * 1024 + wg * 32 + bcol) * D_ + bk;
    const u16* R1 = RT + (size_t)((cb * 2 + 1) * 1024 + wg * 32 + bcol) * D_ + bk;
    #pragma unroll
    for (int kt = 0; kt < 16; ++kt) {
      b0[kt] = *(const short8v*)(R0 + kt * 16);
      b1[kt] = *(const short8v*)(R1 + kt * 16);
    }
  }
  // A-fragment addressing (h in LDS, swizzled)
  int arow = l & 31;
  int abyte = arow * 2048;
  int asw = (arow & 7) << 4;
  int akb = (ks * 256 + (l >> 5) * 8) * 2;
  // tagged-h consumer mapping: j -> row j*4+(tid>>7), 4 u64 words at (tid&127)*4
  int cbase = (tid >> 7) * 512 + (tid & 127) * 4;
  // gate mapping: thread -> (grow, gu), (grow, gu+1)
  int grow = tid >> 4, gu = (tid & 15) * 2;
  const u16* zrow_p = Zx + (size_t)grow * N4_ + wg * 32 + gu;
  u64* hpub = htag + (size_t)grow * 512 + wg * 16 + (tid & 15);

  #pragma unroll 1
  for (int t = 0; t < T_; ++t) {
    // prefetch this thread's Zx[t] gate pre-activations (overlaps the poll)
    const u16* zp = zrow_p + (size_t)t * 32 * N4_;
    u32 zq0 = *(const u32*)(zp);
    u32 zq1 = *(const u32*)(zp + 1024);
    u32 zq2 = *(const u32*)(zp + 2048);
    u32 zq3 = *(const u32*)(zp + 3072);
    __builtin_amdgcn_sched_barrier(0);

    // poll tagged h words (two-phase sweeps keep all pending loads in flight)
    const u64* hb = htag + (size_t)(t & 1) * 16384;
    u32 want = (u32)t;
    u32 hdat[8][4];
    u32 okm = 0u;
    while (okm != 0xFFFFFFFFu) {
      u64 tv[8][4];
      #pragma unroll
      for (int j = 0; j < 8; ++j)
        #pragma unroll
        for (int k = 0; k < 4; ++k)
          if (!((okm >> (j * 4 + k)) & 1u))
            tv[j][k] = __hip_atomic_load(hb + cbase + j * 2048 + k,
                                         __ATOMIC_RELAXED, __HIP_MEMORY_SCOPE_AGENT);
      u32 nm = okm;
      #pragma unroll
      for (int j = 0; j < 8; ++j)
        #pragma unroll
        for (int k = 0; k < 4; ++k)
          if (!((okm >> (j * 4 + k)) & 1u) && (u32)(tv[j][k] >> 32) >= want) {
            hdat[j][k] = (u32)tv[j][k];
            nm |= 1u << (j * 4 + k);
          }
      okm = nm;
    }
    // stage h into swizzled LDS
    #pragma unroll
    for (int j = 0; j < 8; ++j) {
      int byte = j * 8192 + tid * 16;
      int row = byte >> 11;
      u32x4 val;
      val[0] = hdat[j][0]; val[1] = hdat[j][1]; val[2] = hdat[j][2]; val[3] = hdat[j][3];
      *(u32x4*)((char*)h_lds + (byte ^ ((row & 7) << 4))) = val;
    }
    __syncthreads();

    // K-loop: 16 x (1 ds_read_b128 + 2 mfma 32x32x16)
    f32x16 acc0, acc1;
    #pragma unroll
    for (int i = 0; i < 16; ++i) { acc0[i] = 0.f; acc1[i] = 0.f; }
    #pragma unroll
    for (int kt = 0; kt < 16; ++kt) {
      int byte = abyte + akb + kt * 32;
      short8v a = *(const short8v*)((const char*)h_lds + (byte ^ asw));
      acc0 = __builtin_amdgcn_mfma_f32_32x32x16_bf16(a, b0[kt], acc0, 0, 0, 0);
      acc1 = __builtin_amdgcn_mfma_f32_32x32x16_bf16(a, b1[kt], acc1, 0, 0, 0);
    }
    // write K-partials: D layout row=(reg&3)+8*(reg>>2)+4*(lane>>5), col=lane&31
    #pragma unroll
    for (int r = 0; r < 16; ++r) {
      int rowi = (r & 3) + 8 * (r >> 2) + 4 * (l >> 5);
      z_lds[(ks * B_ + rowi) * 129 + (cb * 2 + 0) * 32 + bcol] = acc0[r];
      z_lds[(ks * B_ + rowi) * 129 + (cb * 2 + 1) * 32 + bcol] = acc1[r];
    }
    __syncthreads();

    // gates
    #define ZP(g, hh) ( z_lds[(0*B_+grow)*129 + (g)*32 + gu + (hh)] \
                      + z_lds[(1*B_+grow)*129 + (g)*32 + gu + (hh)] \
                      + z_lds[(2*B_+grow)*129 + (g)*32 + gu + (hh)] \
                      + z_lds[(3*B_+grow)*129 + (g)*32 + gu + (hh)] )
    float zi0 = ZP(0, 0) + bf2f((u16)(zq0 & 0xFFFFu));
    float zf0 = ZP(1, 0) + bf2f((u16)(zq1 & 0xFFFFu));
    float zg0 = ZP(2, 0) + bf2f((u16)(zq2 & 0xFFFFu));
    float zo0 = ZP(3, 0) + bf2f((u16)(zq3 & 0xFFFFu));
    float c0 = c_lds[grow * 32 + gu];
    float cn0 = sigm(zf0) * c0 + sigm(zi0) * tanh_fast(zg0);
    float hn0 = sigm(zo0) * tanh_fast(cn0);
    c_lds[grow * 32 + gu] = cn0;
    float zi1 = ZP(0, 1) + bf2f((u16)(zq0 >> 16));
    float zf1 = ZP(1, 1) + bf2f((u16)(zq1 >> 16));
    float zg1 = ZP(2, 1) + bf2f((u16)(zq2 >> 16));
    float zo1 = ZP(3, 1) + bf2f((u16)(zq3 >> 16));
    float c1 = c_lds[grow * 32 + gu + 1];
    float cn1 = sigm(zf1) * c1 + sigm(zi1) * tanh_fast(zg1);
    float hn1 = sigm(zo1) * tanh_fast(cn1);
    c_lds[grow * 32 + gu + 1] = cn1;
    #undef ZP

    // publish tagged h word (single 8B agent-scope store; no barrier, no flag)
    u32 hpack = (u32)f2bf(hn0) | ((u32)f2bf(hn1) << 16);
    u64 word = ((u64)(u32)(t + 1) << 32) | (u64)hpack;
    __hip_atomic_store(hpub + (size_t)((t + 1) & 1) * 16384, word,
                       __ATOMIC_RELAXED, __HIP_MEMORY_SCOPE_AGENT);
    if (t == T_ - 1) {
      h_last[grow * D_ + wg * 32 + gu]     = hn0;
      h_last[grow * D_ + wg * 32 + gu + 1] = hn1;
    }
  }
}

// ---------------- LN2: out = LN(xn + h_last) fp32 ----------------
__global__ __launch_bounds__(256) void ln2_kernel(const u16* __restrict__ xn,
    const float* __restrict__ h_last, const float* __restrict__ gam,
    const float* __restrict__ bet, float* __restrict__ out) {
  int row = blockIdx.x; int tid = threadIdx.x;
  int bi = row >> 9;
  ushort4v xv = *(const ushort4v*)(xn + (size_t)row * D_ + tid * 4);
  float4 hv = *(const float4*)(h_last + (size_t)bi * D_ + tid * 4);
  float s0 = bf2f(xv.x) + hv.x;
  float s1 = bf2f(xv.y) + hv.y;
  float s2 = bf2f(xv.z) + hv.z;
  float s3 = bf2f(xv.w) + hv.w;
  float s = s0 + s1 + s2 + s3;
  float ss = s0*s0 + s1*s1 + s2*s2 + s3*s3;
  #pragma unroll
  for (int o = 32; o > 0; o >>= 1) { s += __shfl_down(s, o); ss += __shfl_down(ss, o); }
  __shared__ float red[8];
  int w = tid >> 6, l = tid & 63;
  if (l == 0) { red[w] = s; red[4 + w] = ss; }
  __syncthreads();
  s  = red[0] + red[1] + red[2] + red[3];
  ss = red[4] + red[5] + red[6] + red[7];
  float mean = s * (1.f / D_);
  float var  = ss * (1.f / D_) - mean * mean;
  float rstd = rsqrtf(var + 1e-3f);
  float4 g = *(const float4*)(gam + tid * 4);
  float4 b = *(const float4*)(bet + tid * 4);
  float4 o4;
  o4.x = (s0 - mean) * rstd * g.x + b.x;
  o4.y = (s1 - mean) * rstd * g.y + b.y;
  o4.z = (s2 - mean) * rstd * g.z + b.z;
  o4.w = (s3 - mean) * rstd * g.w + b.w;
  *(float4*)(out + (size_t)row * D_ + tid * 4) = o4;
}

extern "C" void kernel_launch(void* const* d_in, const int* in_sizes, int n_in,
                              void* d_out, int out_size, void* d_ws, size_t ws_size,
                              hipStream_t stream) {
  const float* x    = (const float*)d_in[0];
  const float* g1   = (const float*)d_in[1];
  const float* b1   = (const float*)d_in[2];
  const float* Wk   = (const float*)d_in[3];
  const float* Wr   = (const float*)d_in[4];
  const float* bias = (const float*)d_in[5];
  const float* g2   = (const float*)d_in[6];
  const float* b2   = (const float*)d_in[7];
  char* ws = (char*)d_ws;
  u16* xn    = (u16*)(ws + OFF_XN);
  u16* Zx    = (u16*)(ws + OFF_ZX);
  u16* KT    = (u16*)(ws + OFF_KT);
  u16* RT    = (u16*)(ws + OFF_RT);
  u64* htag  = (u64*)(ws + OFF_HT);
  float* hl  = (float*)(ws + OFF_KT);    // aliases KT (dead after gemm_xk)
  float* out = (float*)d_out;

  init_kernel<<<128, 256, 0, stream>>>(htag);
  ln1_kernel<<<B_ * T_, 256, 0, stream>>>(x, g1, b1, xn);
  transpose_bf16<<<dim3(128, 32), dim3(32, 8), 0, stream>>>(Wk, KT);
  transpose_bf16<<<dim3(128, 32), dim3(32, 8), 0, stream>>>(Wr, RT);
  gemm_xk<<<4096, 256, 0, stream>>>(xn, KT, bias, Zx);
  lstm_scan<<<32, 512, 0, stream>>>(Zx, RT, htag, hl);
  ln2_kernel<<<B_ * T_, 256, 0, stream>>>(xn, hl, g2, b2, out);
}

// Round 4
// 2509.433 us; speedup vs baseline: 2.3276x; 2.3276x over previous
//
#include <hip/hip_runtime.h>

typedef unsigned short u16;
typedef unsigned int   u32;
typedef unsigned long long u64;
typedef __attribute__((ext_vector_type(8)))  short  short8v;   // 8 x bf16 (as i16)
typedef __attribute__((ext_vector_type(4)))  float  f32x4;
typedef __attribute__((ext_vector_type(16))) float  f32x16;
typedef __attribute__((ext_vector_type(4)))  unsigned short ushort4v;

#define B_   32
#define T_   512
#define D_   1024
#define N4_  4096

// ---- workspace layout (bytes) ----
#define OFF_XN   0ull                 // xn bf16   [32*512*1024]      33554432
#define OFF_ZX   33554432ull          // Zx bf16   [512][32][1024][4] 134217728  (gate-interleaved)
#define OFF_KT   167772160ull         // kernel^T bf16 [4096][1024]    8388608  (reused as h_last after GEMM)
#define OFF_RT   176160768ull         // recurrent^T bf16 [4096][1024] 8388608
#define OFF_HB   184549376ull         // h double buffer bf16 2*[32][1024] = 131072
#define OFF_FLG  184680448ull         // flags: 32 x 64B-strided u32

__device__ inline u16 f2bf(float f) {
  union { float f; u32 u; } x; x.f = f;
  u32 r = x.u + 0x7FFFu + ((x.u >> 16) & 1u);   // RNE
  return (u16)(r >> 16);
}
__device__ inline float bf2f(u16 h) {
  union { u32 u; float f; } x; x.u = ((u32)h) << 16; return x.f;
}
__device__ inline float sigm(float x) { return 1.f / (1.f + __expf(-x)); }
__device__ inline float tanh_fast(float x) {
  float e = __expf(2.f * x);
  return 1.f - 2.f / (e + 1.f);
}

// ---------------- init: zero h buffers + flags ----------------
__global__ __launch_bounds__(256) void init_kernel(u32* hbuf, u32* flags) {
  int i = blockIdx.x * 256 + threadIdx.x;
  if (i < 32768) hbuf[i] = 0u;       // both parities: 2*32*1024 bf16 = 32768 dwords
  if (i < 32)    flags[i * 16] = 0u;
}

// ---------------- LN1: x fp32 -> xn bf16 ----------------
__global__ __launch_bounds__(256) void ln1_kernel(const float* __restrict__ x,
    const float* __restrict__ gam, const float* __restrict__ bet, u16* __restrict__ xn) {
  int row = blockIdx.x; int tid = threadIdx.x;
  const float* xr = x + (size_t)row * D_;
  float4 v = *(const float4*)(xr + tid * 4);
  float s  = v.x + v.y + v.z + v.w;
  float ss = v.x*v.x + v.y*v.y + v.z*v.z + v.w*v.w;
  #pragma unroll
  for (int o = 32; o > 0; o >>= 1) { s += __shfl_down(s, o); ss += __shfl_down(ss, o); }
  __shared__ float red[8];
  int w = tid >> 6, l = tid & 63;
  if (l == 0) { red[w] = s; red[4 + w] = ss; }
  __syncthreads();
  s  = red[0] + red[1] + red[2] + red[3];
  ss = red[4] + red[5] + red[6] + red[7];
  float mean = s * (1.f / D_);
  float var  = ss * (1.f / D_) - mean * mean;
  float rstd = rsqrtf(var + 1e-3f);
  float4 g = *(const float4*)(gam + tid * 4);
  float4 b = *(const float4*)(bet + tid * 4);
  ushort4v o4;
  o4.x = f2bf((v.x - mean) * rstd * g.x + b.x);
  o4.y = f2bf((v.y - mean) * rstd * g.y + b.y);
  o4.z = f2bf((v.z - mean) * rstd * g.z + b.z);
  o4.w = f2bf((v.w - mean) * rstd * g.w + b.w);
  *(ushort4v*)(xn + (size_t)row * D_ + tid * 4) = o4;
}

// ---------------- transpose [1024][4096] fp32 -> [4096][1024] bf16 ----------------
__global__ __launch_bounds__(256) void transpose_bf16(const float* __restrict__ W, u16* __restrict__ WT) {
  __shared__ float tile[32][33];
  int c0 = blockIdx.x * 32, r0 = blockIdx.y * 32;
  int tx = threadIdx.x, ty = threadIdx.y;
  #pragma unroll
  for (int i = ty; i < 32; i += 8)
    tile[i][tx] = W[(size_t)(r0 + i) * N4_ + c0 + tx];
  __syncthreads();
  #pragma unroll
  for (int i = ty; i < 32; i += 8)
    WT[(size_t)(c0 + i) * D_ + r0 + tx] = f2bf(tile[tx][i]);
}

// ---------------- GEMM: Zx = xn @ kernel + bias  (gate-interleaved output) ----------------
__global__ __launch_bounds__(256) void gemm_xk(const u16* __restrict__ A, const u16* __restrict__ Bt,
    const float* __restrict__ bias, u16* __restrict__ Zx) {
  __shared__ u16 As[128 * 32];
  __shared__ u16 Bs[128 * 32];
  int tid = threadIdx.x;
  int bm = blockIdx.x >> 5, bn = blockIdx.x & 31;
  int w = tid >> 6, l = tid & 63;
  int srow = tid >> 2, sk = (tid & 3) * 8;        // staging: row j*64+srow, k = sk..sk+8
  const u16* Ag = A  + (size_t)(bm * 128 + srow) * D_ + sk;
  const u16* Bg = Bt + (size_t)(bn * 128 + srow) * D_ + sk;
  int sb0 = (srow * 64 + sk * 2)          ^ ((srow & 3) << 4);
  int sb1 = ((srow + 64) * 64 + sk * 2)   ^ ((srow & 3) << 4);
  int wm = w >> 1, wn = w & 1;
  int frow = l & 15, fko = (l >> 4) * 16;         // fragment k byte offset
  f32x4 acc[4][4];
  #pragma unroll
  for (int mi = 0; mi < 4; ++mi)
    #pragma unroll
    for (int ni = 0; ni < 4; ++ni)
      #pragma unroll
      for (int j = 0; j < 4; ++j) acc[mi][ni][j] = 0.f;

  short8v ap0 = *(const short8v*)(Ag);
  short8v ap1 = *(const short8v*)(Ag + 64 * (size_t)D_);
  short8v bp0 = *(const short8v*)(Bg);
  short8v bp1 = *(const short8v*)(Bg + 64 * (size_t)D_);

  for (int kt = 0; kt < 32; ++kt) {
    __syncthreads();
    *(short8v*)((char*)As + sb0) = ap0;
    *(short8v*)((char*)As + sb1) = ap1;
    *(short8v*)((char*)Bs + sb0) = bp0;
    *(short8v*)((char*)Bs + sb1) = bp1;
    __syncthreads();
    if (kt < 31) {
      ap0 = *(const short8v*)(Ag + (kt + 1) * 32);
      ap1 = *(const short8v*)(Ag + 64 * (size_t)D_ + (kt + 1) * 32);
      bp0 = *(const short8v*)(Bg + (kt + 1) * 32);
      bp1 = *(const short8v*)(Bg + 64 * (size_t)D_ + (kt + 1) * 32);
    }
    short8v af[4], bfr[4];
    #pragma unroll
    for (int mi = 0; mi < 4; ++mi) {
      int r = wm * 64 + mi * 16 + frow;
      af[mi] = *(const short8v*)((char*)As + ((r * 64 + fko) ^ ((r & 3) << 4)));
    }
    #pragma unroll
    for (int ni = 0; ni < 4; ++ni) {
      int r = wn * 64 + ni * 16 + frow;
      bfr[ni] = *(const short8v*)((char*)Bs + ((r * 64 + fko) ^ ((r & 3) << 4)));
    }
    #pragma unroll
    for (int mi = 0; mi < 4; ++mi)
      #pragma unroll
      for (int ni = 0; ni < 4; ++ni)
        acc[mi][ni] = __builtin_amdgcn_mfma_f32_16x16x32_bf16(af[mi], bfr[ni], acc[mi][ni], 0, 0, 0);
  }
  // epilogue: +bias, bf16, remap rows to [t][b] and cols to [unit][gate]
  #pragma unroll
  for (int mi = 0; mi < 4; ++mi) {
    #pragma unroll
    for (int ni = 0; ni < 4; ++ni) {
      int col = bn * 128 + wn * 64 + ni * 16 + (l & 15);
      float bv = bias[col];
      int colp = ((col & 1023) << 2) | (col >> 10);   // gate-interleaved
      #pragma unroll
      for (int j = 0; j < 4; ++j) {
        int row = bm * 128 + wm * 64 + mi * 16 + (l >> 4) * 4 + j;
        int zrow = (row & 511) * 32 + (row >> 9);
        Zx[(size_t)zrow * N4_ + colp] = f2bf(acc[mi][ni][j] + bv);
      }
    }
  }
}

// ---------------- persistent LSTM scan ----------------
// 32 WGs x 1024 thr (16 waves = 4 K-splits x 4 gates). WG owns units [wg*32, wg*32+32).
// R^T fragments register-resident (64 VGPR/thread). One gate-cell per thread; c in register.
// Exchange: plain-packed h via agent-scope relaxed atomics + per-WG flag (R2 protocol).
__global__ __launch_bounds__(1024, 4) void lstm_scan(const u16* __restrict__ Zx,
    const u16* __restrict__ RT, u16* hbuf, float* h_last, u32* flags) {
  __shared__ u16   h_lds[B_ * D_];           // 64 KB, XOR-swizzled rows
  __shared__ float z_lds[128 * 136];         // 69.6 KB: [ks*32+row][stride 136]
  int tid = threadIdx.x;
  int wg = blockIdx.x;
  int w = tid >> 6, l = tid & 63;
  int ks = w >> 2, cg = w & 3;               // K-range ks*256..+256, gate cg

  // preload B fragments (R^T) into registers: 16 kt, 64 VGPRs total
  short8v b[16];
  {
    const u16* Rp = RT + (size_t)(cg * 1024 + wg * 32 + (l & 31)) * D_
                  + ks * 256 + (l >> 5) * 8;
    #pragma unroll
    for (int kt = 0; kt < 16; ++kt) b[kt] = *(const short8v*)(Rp + kt * 16);
  }
  // A-fragment addressing (h in LDS, swizzled)
  int arow = l & 31;
  int abase = arow * 2048 + (ks * 256 + (l >> 5) * 8) * 2;
  int asw = (arow & 7) << 4;
  // gate cell: (grow, gu)
  int grow = tid >> 5, gu = tid & 31;
  const u16* zx_p = Zx + (size_t)grow * N4_ + (wg * 32 + gu) * 4;
  int hoff = grow * D_ + wg * 32 + gu;
  float c = 0.f;
  const u32* fp = flags + (size_t)(l & 31) * 16;

  #pragma unroll 1
  for (int t = 0; t < T_; ++t) {
    // prefetch all 4 gate pre-activations (one 8B load, overlaps the poll)
    u64 zq = *(const u64*)(zx_p + (size_t)t * B_ * N4_);
    __builtin_amdgcn_sched_barrier(0);

    // poll: every wave waits until all 32 WGs published h[t]
    while (true) {
      u32 f = __hip_atomic_load(fp, __ATOMIC_RELAXED, __HIP_MEMORY_SCOPE_AGENT);
      if (__all((int)(f >= (u32)t))) break;
      __builtin_amdgcn_s_sleep(1);
    }

    // bulk-load h (64 KB, 8 x 8B coherent loads/thread), stage swizzled into LDS
    const u64* hb = (const u64*)(hbuf + (size_t)(t & 1) * (B_ * D_));
    u64 hv[8];
    #pragma unroll
    for (int j = 0; j < 8; ++j)
      hv[j] = __hip_atomic_load(hb + j * 1024 + tid, __ATOMIC_RELAXED, __HIP_MEMORY_SCOPE_AGENT);
    #pragma unroll
    for (int j = 0; j < 8; ++j) {
      int byte = (j * 1024 + tid) * 8;
      int row = byte >> 11;
      *(u64*)((char*)h_lds + (byte ^ ((row & 7) << 4))) = hv[j];
    }
    __syncthreads();

    // K-loop: 16 x (ds_read_b128 + mfma 32x32x16), register-resident B
    f32x16 acc;
    #pragma unroll
    for (int i = 0; i < 16; ++i) acc[i] = 0.f;
    #pragma unroll
    for (int kt = 0; kt < 16; ++kt) {
      short8v a = *(const short8v*)((const char*)h_lds + ((abase + kt * 32) ^ asw));
      acc = __builtin_amdgcn_mfma_f32_32x32x16_bf16(a, b[kt], acc, 0, 0, 0);
    }
    // write K-partials: D layout row=(r&3)+8*(r>>2)+4*(lane>>5), col=lane&31
    #pragma unroll
    for (int r = 0; r < 16; ++r) {
      int rowD = (r & 3) + 8 * (r >> 2) + 4 * (l >> 5);
      z_lds[(ks * 32 + rowD) * 136 + cg * 32 + (l & 31)] = acc[r];
    }
    __syncthreads();

    // gates: one cell per thread
    float z0 = bf2f((u16)(zq        & 0xFFFFu));
    float z1 = bf2f((u16)((zq >> 16) & 0xFFFFu));
    float z2 = bf2f((u16)((zq >> 32) & 0xFFFFu));
    float z3 = bf2f((u16)((zq >> 48) & 0xFFFFu));
    #pragma unroll
    for (int kss = 0; kss < 4; ++kss) {
      const float* zr = &z_lds[(kss * 32 + grow) * 136 + gu];
      z0 += zr[0]; z1 += zr[32]; z2 += zr[64]; z3 += zr[96];
    }
    float cn = sigm(z1) * c + sigm(z0) * tanh_fast(z2);
    float hn = sigm(z3) * tanh_fast(cn);
    c = cn;

    // publish h (pair lanes -> u32 agent-scope store)
    u32 hw = (u32)f2bf(hn);
    u32 nb = __shfl_down(hw, 1);
    if (!(gu & 1)) {
      u32* dst = (u32*)(hbuf + (size_t)((t + 1) & 1) * (B_ * D_) + hoff);
      __hip_atomic_store(dst, hw | (nb << 16), __ATOMIC_RELAXED, __HIP_MEMORY_SCOPE_AGENT);
    }
    if (t == T_ - 1) h_last[hoff] = hn;
    // drain all waves' stores, then publish the flag
    __syncthreads();
    if (tid == 0)
      __hip_atomic_store(flags + (size_t)wg * 16, (u32)(t + 1),
                         __ATOMIC_RELAXED, __HIP_MEMORY_SCOPE_AGENT);
  }
}

// ---------------- LN2: out = LN(xn + h_last) fp32 ----------------
__global__ __launch_bounds__(256) void ln2_kernel(const u16* __restrict__ xn,
    const float* __restrict__ h_last, const float* __restrict__ gam,
    const float* __restrict__ bet, float* __restrict__ out) {
  int row = blockIdx.x; int tid = threadIdx.x;
  int bi = row >> 9;
  ushort4v xv = *(const ushort4v*)(xn + (size_t)row * D_ + tid * 4);
  float4 hv = *(const float4*)(h_last + (size_t)bi * D_ + tid * 4);
  float s0 = bf2f(xv.x) + hv.x;
  float s1 = bf2f(xv.y) + hv.y;
  float s2 = bf2f(xv.z) + hv.z;
  float s3 = bf2f(xv.w) + hv.w;
  float s = s0 + s1 + s2 + s3;
  float ss = s0*s0 + s1*s1 + s2*s2 + s3*s3;
  #pragma unroll
  for (int o = 32; o > 0; o >>= 1) { s += __shfl_down(s, o); ss += __shfl_down(ss, o); }
  __shared__ float red[8];
  int w = tid >> 6, l = tid & 63;
  if (l == 0) { red[w] = s; red[4 + w] = ss; }
  __syncthreads();
  s  = red[0] + red[1] + red[2] + red[3];
  ss = red[4] + red[5] + red[6] + red[7];
  float mean = s * (1.f / D_);
  float var  = ss * (1.f / D_) - mean * mean;
  float rstd = rsqrtf(var + 1e-3f);
  float4 g = *(const float4*)(gam + tid * 4);
  float4 b = *(const float4*)(bet + tid * 4);
  float4 o4;
  o4.x = (s0 - mean) * rstd * g.x + b.x;
  o4.y = (s1 - mean) * rstd * g.y + b.y;
  o4.z = (s2 - mean) * rstd * g.z + b.z;
  o4.w = (s3 - mean) * rstd * g.w + b.w;
  *(float4*)(out + (size_t)row * D_ + tid * 4) = o4;
}

extern "C" void kernel_launch(void* const* d_in, const int* in_sizes, int n_in,
                              void* d_out, int out_size, void* d_ws, size_t ws_size,
                              hipStream_t stream) {
  const float* x    = (const float*)d_in[0];
  const float* g1   = (const float*)d_in[1];
  const float* b1   = (const float*)d_in[2];
  const float* Wk   = (const float*)d_in[3];
  const float* Wr   = (const float*)d_in[4];
  const float* bias = (const float*)d_in[5];
  const float* g2   = (const float*)d_in[6];
  const float* b2   = (const float*)d_in[7];
  char* ws = (char*)d_ws;
  u16* xn    = (u16*)(ws + OFF_XN);
  u16* Zx    = (u16*)(ws + OFF_ZX);
  u16* KT    = (u16*)(ws + OFF_KT);
  u16* RT    = (u16*)(ws + OFF_RT);
  u16* hbuf  = (u16*)(ws + OFF_HB);
  u32* flg   = (u32*)(ws + OFF_FLG);
  float* hl  = (float*)(ws + OFF_KT);    // aliases KT (dead after gemm_xk)
  float* out = (float*)d_out;

  init_kernel<<<128, 256, 0, stream>>>((u32*)hbuf, flg);
  ln1_kernel<<<B_ * T_, 256, 0, stream>>>(x, g1, b1, xn);
  transpose_bf16<<<dim3(128, 32), dim3(32, 8), 0, stream>>>(Wk, KT);
  transpose_bf16<<<dim3(128, 32), dim3(32, 8), 0, stream>>>(Wr, RT);
  gemm_xk<<<4096, 256, 0, stream>>>(xn, KT, bias, Zx);
  lstm_scan<<<32, 1024, 0, stream>>>(Zx, RT, hbuf, hl, flg);
  ln2_kernel<<<B_ * T_, 256, 0, stream>>>(xn, hl, g2, b2, out);
}

// Round 5
// 2495.890 us; speedup vs baseline: 2.3402x; 1.0054x over previous
//
#include <hip/hip_runtime.h>

typedef unsigned short u16;
typedef unsigned int   u32;
typedef unsigned long long u64;
typedef __attribute__((ext_vector_type(8)))  short  short8v;   // 8 x bf16 (as i16)
typedef __attribute__((ext_vector_type(4)))  float  f32x4;
typedef __attribute__((ext_vector_type(16))) float  f32x16;
typedef __attribute__((ext_vector_type(4)))  unsigned short ushort4v;

#define B_   32
#define T_   512
#define D_   1024
#define N4_  4096

// ---- workspace layout (bytes) ----
#define OFF_XN   0ull                 // xn bf16   [32*512*1024]      33554432
#define OFF_ZX   33554432ull          // Zx bf16   [512][32][1024][4] 134217728  (gate-interleaved)
#define OFF_KT   167772160ull         // kernel^T bf16 [4096][1024]    8388608  (reused as h_last after GEMM)
#define OFF_RT   176160768ull         // recurrent^T bf16 [4096][1024] 8388608
#define OFF_HB   184549376ull         // h double buffer bf16 2*[32][1024] = 131072
#define OFF_FLG  184680448ull         // flags: 32 x 64B-strided u32

__device__ inline u16 f2bf(float f) {
  union { float f; u32 u; } x; x.f = f;
  u32 r = x.u + 0x7FFFu + ((x.u >> 16) & 1u);   // RNE
  return (u16)(r >> 16);
}
__device__ inline float bf2f(u16 h) {
  union { u32 u; float f; } x; x.u = ((u32)h) << 16; return x.f;
}
__device__ inline float sigm(float x) { return 1.f / (1.f + __expf(-x)); }
__device__ inline float tanh_fast(float x) {
  float e = __expf(2.f * x);
  return 1.f - 2.f / (e + 1.f);
}

// ---------------- init: zero h buffers + flags ----------------
__global__ __launch_bounds__(256) void init_kernel(u32* hbuf, u32* flags) {
  int i = blockIdx.x * 256 + threadIdx.x;
  if (i < 32768) hbuf[i] = 0u;       // both parities: 2*32*1024 bf16 = 32768 dwords
  if (i < 32)    flags[i * 16] = 0u;
}

// ---------------- LN1: x fp32 -> xn bf16 ----------------
__global__ __launch_bounds__(256) void ln1_kernel(const float* __restrict__ x,
    const float* __restrict__ gam, const float* __restrict__ bet, u16* __restrict__ xn) {
  int row = blockIdx.x; int tid = threadIdx.x;
  const float* xr = x + (size_t)row * D_;
  float4 v = *(const float4*)(xr + tid * 4);
  float s  = v.x + v.y + v.z + v.w;
  float ss = v.x*v.x + v.y*v.y + v.z*v.z + v.w*v.w;
  #pragma unroll
  for (int o = 32; o > 0; o >>= 1) { s += __shfl_down(s, o); ss += __shfl_down(ss, o); }
  __shared__ float red[8];
  int w = tid >> 6, l = tid & 63;
  if (l == 0) { red[w] = s; red[4 + w] = ss; }
  __syncthreads();
  s  = red[0] + red[1] + red[2] + red[3];
  ss = red[4] + red[5] + red[6] + red[7];
  float mean = s * (1.f / D_);
  float var  = ss * (1.f / D_) - mean * mean;
  float rstd = rsqrtf(var + 1e-3f);
  float4 g = *(const float4*)(gam + tid * 4);
  float4 b = *(const float4*)(bet + tid * 4);
  ushort4v o4;
  o4.x = f2bf((v.x - mean) * rstd * g.x + b.x);
  o4.y = f2bf((v.y - mean) * rstd * g.y + b.y);
  o4.z = f2bf((v.z - mean) * rstd * g.z + b.z);
  o4.w = f2bf((v.w - mean) * rstd * g.w + b.w);
  *(ushort4v*)(xn + (size_t)row * D_ + tid * 4) = o4;
}

// ---------------- transpose [1024][4096] fp32 -> [4096][1024] bf16 ----------------
__global__ __launch_bounds__(256) void transpose_bf16(const float* __restrict__ W, u16* __restrict__ WT) {
  __shared__ float tile[32][33];
  int c0 = blockIdx.x * 32, r0 = blockIdx.y * 32;
  int tx = threadIdx.x, ty = threadIdx.y;
  #pragma unroll
  for (int i = ty; i < 32; i += 8)
    tile[i][tx] = W[(size_t)(r0 + i) * N4_ + c0 + tx];
  __syncthreads();
  #pragma unroll
  for (int i = ty; i < 32; i += 8)
    WT[(size_t)(c0 + i) * D_ + r0 + tx] = f2bf(tile[tx][i]);
}

// ---------------- GEMM: Zx = xn @ kernel + bias  (gate-interleaved output) ----------------
__global__ __launch_bounds__(256) void gemm_xk(const u16* __restrict__ A, const u16* __restrict__ Bt,
    const float* __restrict__ bias, u16* __restrict__ Zx) {
  __shared__ u16 As[128 * 32];
  __shared__ u16 Bs[128 * 32];
  int tid = threadIdx.x;
  int bm = blockIdx.x >> 5, bn = blockIdx.x & 31;
  int w = tid >> 6, l = tid & 63;
  int srow = tid >> 2, sk = (tid & 3) * 8;        // staging: row j*64+srow, k = sk..sk+8
  const u16* Ag = A  + (size_t)(bm * 128 + srow) * D_ + sk;
  const u16* Bg = Bt + (size_t)(bn * 128 + srow) * D_ + sk;
  int sb0 = (srow * 64 + sk * 2)          ^ ((srow & 3) << 4);
  int sb1 = ((srow + 64) * 64 + sk * 2)   ^ ((srow & 3) << 4);
  int wm = w >> 1, wn = w & 1;
  int frow = l & 15, fko = (l >> 4) * 16;         // fragment k byte offset
  f32x4 acc[4][4];
  #pragma unroll
  for (int mi = 0; mi < 4; ++mi)
    #pragma unroll
    for (int ni = 0; ni < 4; ++ni)
      #pragma unroll
      for (int j = 0; j < 4; ++j) acc[mi][ni][j] = 0.f;

  short8v ap0 = *(const short8v*)(Ag);
  short8v ap1 = *(const short8v*)(Ag + 64 * (size_t)D_);
  short8v bp0 = *(const short8v*)(Bg);
  short8v bp1 = *(const short8v*)(Bg + 64 * (size_t)D_);

  for (int kt = 0; kt < 32; ++kt) {
    __syncthreads();
    *(short8v*)((char*)As + sb0) = ap0;
    *(short8v*)((char*)As + sb1) = ap1;
    *(short8v*)((char*)Bs + sb0) = bp0;
    *(short8v*)((char*)Bs + sb1) = bp1;
    __syncthreads();
    if (kt < 31) {
      ap0 = *(const short8v*)(Ag + (kt + 1) * 32);
      ap1 = *(const short8v*)(Ag + 64 * (size_t)D_ + (kt + 1) * 32);
      bp0 = *(const short8v*)(Bg + (kt + 1) * 32);
      bp1 = *(const short8v*)(Bg + 64 * (size_t)D_ + (kt + 1) * 32);
    }
    short8v af[4], bfr[4];
    #pragma unroll
    for (int mi = 0; mi < 4; ++mi) {
      int r = wm * 64 + mi * 16 + frow;
      af[mi] = *(const short8v*)((char*)As + ((r * 64 + fko) ^ ((r & 3) << 4)));
    }
    #pragma unroll
    for (int ni = 0; ni < 4; ++ni) {
      int r = wn * 64 + ni * 16 + frow;
      bfr[ni] = *(const short8v*)((char*)Bs + ((r * 64 + fko) ^ ((r & 3) << 4)));
    }
    #pragma unroll
    for (int mi = 0; mi < 4; ++mi)
      #pragma unroll
      for (int ni = 0; ni < 4; ++ni)
        acc[mi][ni] = __builtin_amdgcn_mfma_f32_16x16x32_bf16(af[mi], bfr[ni], acc[mi][ni], 0, 0, 0);
  }
  // epilogue: +bias, bf16, remap rows to [t][b] and cols to [unit][gate]
  #pragma unroll
  for (int mi = 0; mi < 4; ++mi) {
    #pragma unroll
    for (int ni = 0; ni < 4; ++ni) {
      int col = bn * 128 + wn * 64 + ni * 16 + (l & 15);
      float bv = bias[col];
      int colp = ((col & 1023) << 2) | (col >> 10);   // gate-interleaved
      #pragma unroll
      for (int j = 0; j < 4; ++j) {
        int row = bm * 128 + wm * 64 + mi * 16 + (l >> 4) * 4 + j;
        int zrow = (row & 511) * 32 + (row >> 9);
        Zx[(size_t)zrow * N4_ + colp] = f2bf(acc[mi][ni][j] + bv);
      }
    }
  }
}

// ---------------- persistent LSTM scan ----------------
// 32 WGs x 1024 thr (16 waves = 4 K-splits x 4 gates). WG owns units [wg*32, wg*32+32).
// R^T fragments PINNED register-resident via empty inline-asm (compiler otherwise sinks
// the loads into the K-loop and re-reads 256KB/WG/step from L2 — R4 post-mortem).
// Exchange: plain-packed h via agent-scope relaxed atomics + per-WG flag.
__global__ __launch_bounds__(1024, 4) void lstm_scan(const u16* __restrict__ Zx,
    const u16* __restrict__ RT, u16* hbuf, float* h_last, u32* flags) {
  __shared__ u16   h_lds[B_ * D_];           // 64 KB, XOR-swizzled rows
  __shared__ float z_lds[128 * 136];         // 69.6 KB: [ks*32+row][stride 136]
  int tid = threadIdx.x;
  int wg = blockIdx.x;
  int w = tid >> 6, l = tid & 63;
  int ks = w >> 2, cg = w & 3;               // K-range ks*256..+256, gate cg

  // preload B fragments (R^T) into registers: 16 kt, 64 VGPRs total
  short8v b[16];
  {
    const u16* Rp = RT + (size_t)(cg * 1024 + wg * 32 + (l & 31)) * D_
                  + ks * 256 + (l >> 5) * 8;
    #pragma unroll
    for (int kt = 0; kt < 16; ++kt) b[kt] = *(const short8v*)(Rp + kt * 16);
  }
  // PIN: empty asm redefines each fragment -> cannot be rematerialized from memory,
  // must stay live in VGPRs across the whole t-loop.
  #pragma unroll
  for (int kt = 0; kt < 16; ++kt) asm volatile("" : "+v"(b[kt]));

  // A-fragment addressing (h in LDS, swizzled)
  int arow = l & 31;
  int abase = arow * 2048 + (ks * 256 + (l >> 5) * 8) * 2;
  int asw = (arow & 7) << 4;
  // gate cell: (grow, gu)
  int grow = tid >> 5, gu = tid & 31;
  const u16* zx_p = Zx + (size_t)grow * N4_ + (wg * 32 + gu) * 4;
  int hoff = grow * D_ + wg * 32 + gu;
  float c = 0.f;
  const u32* fp = flags + (size_t)(l & 31) * 16;

  #pragma unroll 1
  for (int t = 0; t < T_; ++t) {
    // prefetch all 4 gate pre-activations (one 8B load, overlaps the poll)
    u64 zq = *(const u64*)(zx_p + (size_t)t * B_ * N4_);
    __builtin_amdgcn_sched_barrier(0);

    // poll: every wave waits until all 32 WGs published h[t]
    while (true) {
      u32 f = __hip_atomic_load(fp, __ATOMIC_RELAXED, __HIP_MEMORY_SCOPE_AGENT);
      if (__all((int)(f >= (u32)t))) break;
      __builtin_amdgcn_s_sleep(1);
    }

    // bulk-load h (64 KB, 8 x 8B coherent loads/thread), stage swizzled into LDS
    const u64* hb = (const u64*)(hbuf + (size_t)(t & 1) * (B_ * D_));
    u64 hv[8];
    #pragma unroll
    for (int j = 0; j < 8; ++j)
      hv[j] = __hip_atomic_load(hb + j * 1024 + tid, __ATOMIC_RELAXED, __HIP_MEMORY_SCOPE_AGENT);
    #pragma unroll
    for (int j = 0; j < 8; ++j) {
      int byte = (j * 1024 + tid) * 8;
      int row = byte >> 11;
      *(u64*)((char*)h_lds + (byte ^ ((row & 7) << 4))) = hv[j];
    }
    __syncthreads();

    // K-loop: 16 x (ds_read_b128 + mfma 32x32x16), register-resident B
    f32x16 acc;
    #pragma unroll
    for (int i = 0; i < 16; ++i) acc[i] = 0.f;
    #pragma unroll
    for (int kt = 0; kt < 16; ++kt) {
      short8v a = *(const short8v*)((const char*)h_lds + ((abase + kt * 32) ^ asw));
      acc = __builtin_amdgcn_mfma_f32_32x32x16_bf16(a, b[kt], acc, 0, 0, 0);
    }
    // write K-partials: D layout row=(r&3)+8*(r>>2)+4*(lane>>5), col=lane&31
    #pragma unroll
    for (int r = 0; r < 16; ++r) {
      int rowD = (r & 3) + 8 * (r >> 2) + 4 * (l >> 5);
      z_lds[(ks * 32 + rowD) * 136 + cg * 32 + (l & 31)] = acc[r];
    }
    __syncthreads();

    // gates: one cell per thread
    float z0 = bf2f((u16)(zq        & 0xFFFFu));
    float z1 = bf2f((u16)((zq >> 16) & 0xFFFFu));
    float z2 = bf2f((u16)((zq >> 32) & 0xFFFFu));
    float z3 = bf2f((u16)((zq >> 48) & 0xFFFFu));
    #pragma unroll
    for (int kss = 0; kss < 4; ++kss) {
      const float* zr = &z_lds[(kss * 32 + grow) * 136 + gu];
      z0 += zr[0]; z1 += zr[32]; z2 += zr[64]; z3 += zr[96];
    }
    float cn = sigm(z1) * c + sigm(z0) * tanh_fast(z2);
    float hn = sigm(z3) * tanh_fast(cn);
    c = cn;

    // publish h (pair lanes -> u32 agent-scope store)
    u32 hw = (u32)f2bf(hn);
    u32 nb = __shfl_down(hw, 1);
    if (!(gu & 1)) {
      u32* dst = (u32*)(hbuf + (size_t)((t + 1) & 1) * (B_ * D_) + hoff);
      __hip_atomic_store(dst, hw | (nb << 16), __ATOMIC_RELAXED, __HIP_MEMORY_SCOPE_AGENT);
    }
    if (t == T_ - 1) h_last[hoff] = hn;
    // drain all waves' stores, then publish the flag
    __syncthreads();
    if (tid == 0)
      __hip_atomic_store(flags + (size_t)wg * 16, (u32)(t + 1),
                         __ATOMIC_RELAXED, __HIP_MEMORY_SCOPE_AGENT);
  }
}

// ---------------- LN2: out = LN(xn + h_last) fp32 ----------------
__global__ __launch_bounds__(256) void ln2_kernel(const u16* __restrict__ xn,
    const float* __restrict__ h_last, const float* __restrict__ gam,
    const float* __restrict__ bet, float* __restrict__ out) {
  int row = blockIdx.x; int tid = threadIdx.x;
  int bi = row >> 9;
  ushort4v xv = *(const ushort4v*)(xn + (size_t)row * D_ + tid * 4);
  float4 hv = *(const float4*)(h_last + (size_t)bi * D_ + tid * 4);
  float s0 = bf2f(xv.x) + hv.x;
  float s1 = bf2f(xv.y) + hv.y;
  float s2 = bf2f(xv.z) + hv.z;
  float s3 = bf2f(xv.w) + hv.w;
  float s = s0 + s1 + s2 + s3;
  float ss = s0*s0 + s1*s1 + s2*s2 + s3*s3;
  #pragma unroll
  for (int o = 32; o > 0; o >>= 1) { s += __shfl_down(s, o); ss += __shfl_down(ss, o); }
  __shared__ float red[8];
  int w = tid >> 6, l = tid & 63;
  if (l == 0) { red[w] = s; red[4 + w] = ss; }
  __syncthreads();
  s  = red[0] + red[1] + red[2] + red[3];
  ss = red[4] + red[5] + red[6] + red[7];
  float mean = s * (1.f / D_);
  float var  = ss * (1.f / D_) - mean * mean;
  float rstd = rsqrtf(var + 1e-3f);
  float4 g = *(const float4*)(gam + tid * 4);
  float4 b = *(const float4*)(bet + tid * 4);
  float4 o4;
  o4.x = (s0 - mean) * rstd * g.x + b.x;
  o4.y = (s1 - mean) * rstd * g.y + b.y;
  o4.z = (s2 - mean) * rstd * g.z + b.z;
  o4.w = (s3 - mean) * rstd * g.w + b.w;
  *(float4*)(out + (size_t)row * D_ + tid * 4) = o4;
}

extern "C" void kernel_launch(void* const* d_in, const int* in_sizes, int n_in,
                              void* d_out, int out_size, void* d_ws, size_t ws_size,
                              hipStream_t stream) {
  const float* x    = (const float*)d_in[0];
  const float* g1   = (const float*)d_in[1];
  const float* b1   = (const float*)d_in[2];
  const float* Wk   = (const float*)d_in[3];
  const float* Wr   = (const float*)d_in[4];
  const float* bias = (const float*)d_in[5];
  const float* g2   = (const float*)d_in[6];
  const float* b2   = (const float*)d_in[7];
  char* ws = (char*)d_ws;
  u16* xn    = (u16*)(ws + OFF_XN);
  u16* Zx    = (u16*)(ws + OFF_ZX);
  u16* KT    = (u16*)(ws + OFF_KT);
  u16* RT    = (u16*)(ws + OFF_RT);
  u16* hbuf  = (u16*)(ws + OFF_HB);
  u32* flg   = (u32*)(ws + OFF_FLG);
  float* hl  = (float*)(ws + OFF_KT);    // aliases KT (dead after gemm_xk)
  float* out = (float*)d_out;

  init_kernel<<<128, 256, 0, stream>>>((u32*)hbuf, flg);
  ln1_kernel<<<B_ * T_, 256, 0, stream>>>(x, g1, b1, xn);
  transpose_bf16<<<dim3(128, 32), dim3(32, 8), 0, stream>>>(Wk, KT);
  transpose_bf16<<<dim3(128, 32), dim3(32, 8), 0, stream>>>(Wr, RT);
  gemm_xk<<<4096, 256, 0, stream>>>(xn, KT, bias, Zx);
  lstm_scan<<<32, 1024, 0, stream>>>(Zx, RT, hbuf, hl, flg);
  ln2_kernel<<<B_ * T_, 256, 0, stream>>>(xn, hl, g2, b2, out);
}

// Round 6
// 2318.307 us; speedup vs baseline: 2.5195x; 1.0766x over previous
//
#include <hip/hip_runtime.h>

typedef unsigned short u16;
typedef unsigned int   u32;
typedef unsigned long long u64;
typedef __attribute__((ext_vector_type(8)))  short  short8v;   // 8 x bf16 (as i16)
typedef __attribute__((ext_vector_type(4)))  float  f32x4;
typedef __attribute__((ext_vector_type(16))) float  f32x16;
typedef __attribute__((ext_vector_type(4)))  unsigned short ushort4v;
typedef __attribute__((ext_vector_type(4)))  u32 u32x4;

#define B_   32
#define T_   512
#define D_   1024
#define N4_  4096

// ---- workspace layout (bytes) ----
#define OFF_XN   0ull                 // xn bf16   [32*512*1024]      33554432
#define OFF_ZX   33554432ull          // Zx bf16   [512][32][1024][4] 134217728  (gate-interleaved)
#define OFF_KT   167772160ull         // kernel^T bf16 [4096][1024]    8388608  (reused as h_last after GEMM)
#define OFF_RT   176160768ull         // recurrent^T bf16 [4096][1024] 8388608
#define OFF_HB   184549376ull         // h double buffer bf16 2*[32][1024] = 131072
#define OFF_FLG  184680448ull         // flags: 32 x 64B-strided u32

__device__ inline u16 f2bf(float f) {
  union { float f; u32 u; } x; x.f = f;
  u32 r = x.u + 0x7FFFu + ((x.u >> 16) & 1u);   // RNE
  return (u16)(r >> 16);
}
__device__ inline float bf2f(u16 h) {
  union { u32 u; float f; } x; x.u = ((u32)h) << 16; return x.f;
}
__device__ inline float sigm(float x) { return 1.f / (1.f + __expf(-x)); }
__device__ inline float tanh_fast(float x) {
  float e = __expf(2.f * x);
  return 1.f - 2.f / (e + 1.f);
}

// ---------------- init: zero h buffers + flags ----------------
__global__ __launch_bounds__(256) void init_kernel(u32* hbuf, u32* flags) {
  int i = blockIdx.x * 256 + threadIdx.x;
  if (i < 32768) hbuf[i] = 0u;       // both parities: 2*32*1024 bf16 = 32768 dwords
  if (i < 32)    flags[i * 16] = 0u;
}

// ---------------- LN1: x fp32 -> xn bf16 ----------------
__global__ __launch_bounds__(256) void ln1_kernel(const float* __restrict__ x,
    const float* __restrict__ gam, const float* __restrict__ bet, u16* __restrict__ xn) {
  int row = blockIdx.x; int tid = threadIdx.x;
  const float* xr = x + (size_t)row * D_;
  float4 v = *(const float4*)(xr + tid * 4);
  float s  = v.x + v.y + v.z + v.w;
  float ss = v.x*v.x + v.y*v.y + v.z*v.z + v.w*v.w;
  #pragma unroll
  for (int o = 32; o > 0; o >>= 1) { s += __shfl_down(s, o); ss += __shfl_down(ss, o); }
  __shared__ float red[8];
  int w = tid >> 6, l = tid & 63;
  if (l == 0) { red[w] = s; red[4 + w] = ss; }
  __syncthreads();
  s  = red[0] + red[1] + red[2] + red[3];
  ss = red[4] + red[5] + red[6] + red[7];
  float mean = s * (1.f / D_);
  float var  = ss * (1.f / D_) - mean * mean;
  float rstd = rsqrtf(var + 1e-3f);
  float4 g = *(const float4*)(gam + tid * 4);
  float4 b = *(const float4*)(bet + tid * 4);
  ushort4v o4;
  o4.x = f2bf((v.x - mean) * rstd * g.x + b.x);
  o4.y = f2bf((v.y - mean) * rstd * g.y + b.y);
  o4.z = f2bf((v.z - mean) * rstd * g.z + b.z);
  o4.w = f2bf((v.w - mean) * rstd * g.w + b.w);
  *(ushort4v*)(xn + (size_t)row * D_ + tid * 4) = o4;
}

// ---------------- transpose [1024][4096] fp32 -> [4096][1024] bf16 ----------------
__global__ __launch_bounds__(256) void transpose_bf16(const float* __restrict__ W, u16* __restrict__ WT) {
  __shared__ float tile[32][33];
  int c0 = blockIdx.x * 32, r0 = blockIdx.y * 32;
  int tx = threadIdx.x, ty = threadIdx.y;
  #pragma unroll
  for (int i = ty; i < 32; i += 8)
    tile[i][tx] = W[(size_t)(r0 + i) * N4_ + c0 + tx];
  __syncthreads();
  #pragma unroll
  for (int i = ty; i < 32; i += 8)
    WT[(size_t)(c0 + i) * D_ + r0 + tx] = f2bf(tile[tx][i]);
}

// ---------------- GEMM: Zx = xn @ kernel + bias  (gate-interleaved output) ----------------
__global__ __launch_bounds__(256) void gemm_xk(const u16* __restrict__ A, const u16* __restrict__ Bt,
    const float* __restrict__ bias, u16* __restrict__ Zx) {
  __shared__ u16 As[128 * 32];
  __shared__ u16 Bs[128 * 32];
  int tid = threadIdx.x;
  int bm = blockIdx.x >> 5, bn = blockIdx.x & 31;
  int w = tid >> 6, l = tid & 63;
  int srow = tid >> 2, sk = (tid & 3) * 8;        // staging: row j*64+srow, k = sk..sk+8
  const u16* Ag = A  + (size_t)(bm * 128 + srow) * D_ + sk;
  const u16* Bg = Bt + (size_t)(bn * 128 + srow) * D_ + sk;
  int sb0 = (srow * 64 + sk * 2)          ^ ((srow & 3) << 4);
  int sb1 = ((srow + 64) * 64 + sk * 2)   ^ ((srow & 3) << 4);
  int wm = w >> 1, wn = w & 1;
  int frow = l & 15, fko = (l >> 4) * 16;         // fragment k byte offset
  f32x4 acc[4][4];
  #pragma unroll
  for (int mi = 0; mi < 4; ++mi)
    #pragma unroll
    for (int ni = 0; ni < 4; ++ni)
      #pragma unroll
      for (int j = 0; j < 4; ++j) acc[mi][ni][j] = 0.f;

  short8v ap0 = *(const short8v*)(Ag);
  short8v ap1 = *(const short8v*)(Ag + 64 * (size_t)D_);
  short8v bp0 = *(const short8v*)(Bg);
  short8v bp1 = *(const short8v*)(Bg + 64 * (size_t)D_);

  for (int kt = 0; kt < 32; ++kt) {
    __syncthreads();
    *(short8v*)((char*)As + sb0) = ap0;
    *(short8v*)((char*)As + sb1) = ap1;
    *(short8v*)((char*)Bs + sb0) = bp0;
    *(short8v*)((char*)Bs + sb1) = bp1;
    __syncthreads();
    if (kt < 31) {
      ap0 = *(const short8v*)(Ag + (kt + 1) * 32);
      ap1 = *(const short8v*)(Ag + 64 * (size_t)D_ + (kt + 1) * 32);
      bp0 = *(const short8v*)(Bg + (kt + 1) * 32);
      bp1 = *(const short8v*)(Bg + 64 * (size_t)D_ + (kt + 1) * 32);
    }
    short8v af[4], bfr[4];
    #pragma unroll
    for (int mi = 0; mi < 4; ++mi) {
      int r = wm * 64 + mi * 16 + frow;
      af[mi] = *(const short8v*)((char*)As + ((r * 64 + fko) ^ ((r & 3) << 4)));
    }
    #pragma unroll
    for (int ni = 0; ni < 4; ++ni) {
      int r = wn * 64 + ni * 16 + frow;
      bfr[ni] = *(const short8v*)((char*)Bs + ((r * 64 + fko) ^ ((r & 3) << 4)));
    }
    #pragma unroll
    for (int mi = 0; mi < 4; ++mi)
      #pragma unroll
      for (int ni = 0; ni < 4; ++ni)
        acc[mi][ni] = __builtin_amdgcn_mfma_f32_16x16x32_bf16(af[mi], bfr[ni], acc[mi][ni], 0, 0, 0);
  }
  // epilogue: +bias, bf16, remap rows to [t][b] and cols to [unit][gate]
  #pragma unroll
  for (int mi = 0; mi < 4; ++mi) {
    #pragma unroll
    for (int ni = 0; ni < 4; ++ni) {
      int col = bn * 128 + wn * 64 + ni * 16 + (l & 15);
      float bv = bias[col];
      int colp = ((col & 1023) << 2) | (col >> 10);   // gate-interleaved
      #pragma unroll
      for (int j = 0; j < 4; ++j) {
        int row = bm * 128 + wm * 64 + mi * 16 + (l >> 4) * 4 + j;
        int zrow = (row & 511) * 32 + (row >> 9);
        Zx[(size_t)zrow * N4_ + colp] = f2bf(acc[mi][ni][j] + bv);
      }
    }
  }
}

// ---------------- persistent LSTM scan ----------------
// 32 WGs x 1024 thr (16 waves = 4 K-splits x 4 gates). WG owns units [wg*32, wg*32+32).
// Exchange protocol v3: wave0-only flag poll (16x less MALL traffic) + raw s_barrier
// release; bulk h load via 16B global_load_dwordx4 sc0 sc1 (4x fewer coherent requests).
__global__ __launch_bounds__(1024, 4) void lstm_scan(const u16* __restrict__ Zx,
    const u16* __restrict__ RT, u16* hbuf, float* h_last, u32* flags) {
  __shared__ u16   h_lds[B_ * D_];           // 64 KB, XOR-swizzled rows
  __shared__ float z_lds[128 * 136];         // 69.6 KB: [ks*32+row][stride 136]
  int tid = threadIdx.x;
  int wg = blockIdx.x;
  int w = tid >> 6, l = tid & 63;
  int ks = w >> 2, cg = w & 3;               // K-range ks*256..+256, gate cg

  // preload B fragments (R^T) into registers: 16 kt
  short8v b[16];
  {
    const u16* Rp = RT + (size_t)(cg * 1024 + wg * 32 + (l & 31)) * D_
                  + ks * 256 + (l >> 5) * 8;
    #pragma unroll
    for (int kt = 0; kt < 16; ++kt) b[kt] = *(const short8v*)(Rp + kt * 16);
  }
  #pragma unroll
  for (int kt = 0; kt < 16; ++kt) asm volatile("" : "+v"(b[kt]));

  // A-fragment addressing (h in LDS, swizzled)
  int arow = l & 31;
  int abase = arow * 2048 + (ks * 256 + (l >> 5) * 8) * 2;
  int asw = (arow & 7) << 4;
  // gate cell: (grow, gu)
  int grow = tid >> 5, gu = tid & 31;
  const u16* zx_p = Zx + (size_t)grow * N4_ + (wg * 32 + gu) * 4;
  int hoff = grow * D_ + wg * 32 + gu;
  float c = 0.f;
  const u32* fp = flags + (size_t)(l & 31) * 16;

  #pragma unroll 1
  for (int t = 0; t < T_; ++t) {
    // prefetch all 4 gate pre-activations (one 8B load; stays in flight across s_barrier)
    u64 zq = *(const u64*)(zx_p + (size_t)t * B_ * N4_);
    __builtin_amdgcn_sched_barrier(0);

    // wave0 polls the 32 per-WG flags; raw s_barrier releases the other 15 waves
    if (w == 0) {
      while (true) {
        u32 f = __hip_atomic_load(fp, __ATOMIC_RELAXED, __HIP_MEMORY_SCOPE_AGENT);
        if (__all((int)(f >= (u32)t))) break;
      }
    }
    __builtin_amdgcn_s_barrier();
    __builtin_amdgcn_sched_barrier(0);

    // bulk-load h: 4 x 16B coherent loads per thread (sc0 sc1 -> bypass stale L1/L2)
    const char* hbp = (const char*)hbuf + (size_t)(t & 1) * 65536;
    u32x4 hv[4];
    #pragma unroll
    for (int j = 0; j < 4; ++j) {
      const char* p = hbp + j * 16384 + tid * 16;
      asm volatile("global_load_dwordx4 %0, %1, off sc0 sc1"
                   : "=&v"(hv[j]) : "v"(p) : "memory");
    }
    asm volatile("s_waitcnt vmcnt(0)" ::: "memory");
    __builtin_amdgcn_sched_barrier(0);
    #pragma unroll
    for (int j = 0; j < 4; ++j) {
      int byte = j * 16384 + tid * 16;
      int row = byte >> 11;
      *(u32x4*)((char*)h_lds + (byte ^ ((row & 7) << 4))) = hv[j];
    }
    __syncthreads();

    // K-loop: 16 x (ds_read_b128 + mfma 32x32x16)
    f32x16 acc;
    #pragma unroll
    for (int i = 0; i < 16; ++i) acc[i] = 0.f;
    #pragma unroll
    for (int kt = 0; kt < 16; ++kt) {
      short8v a = *(const short8v*)((const char*)h_lds + ((abase + kt * 32) ^ asw));
      acc = __builtin_amdgcn_mfma_f32_32x32x16_bf16(a, b[kt], acc, 0, 0, 0);
    }
    // write K-partials: D layout row=(r&3)+8*(r>>2)+4*(lane>>5), col=lane&31
    #pragma unroll
    for (int r = 0; r < 16; ++r) {
      int rowD = (r & 3) + 8 * (r >> 2) + 4 * (l >> 5);
      z_lds[(ks * 32 + rowD) * 136 + cg * 32 + (l & 31)] = acc[r];
    }
    __syncthreads();

    // gates: one cell per thread
    float z0 = bf2f((u16)(zq        & 0xFFFFu));
    float z1 = bf2f((u16)((zq >> 16) & 0xFFFFu));
    float z2 = bf2f((u16)((zq >> 32) & 0xFFFFu));
    float z3 = bf2f((u16)((zq >> 48) & 0xFFFFu));
    #pragma unroll
    for (int kss = 0; kss < 4; ++kss) {
      const float* zr = &z_lds[(kss * 32 + grow) * 136 + gu];
      z0 += zr[0]; z1 += zr[32]; z2 += zr[64]; z3 += zr[96];
    }
    float cn = sigm(z1) * c + sigm(z0) * tanh_fast(z2);
    float hn = sigm(z3) * tanh_fast(cn);
    c = cn;

    // publish h (pair lanes -> u32 agent-scope store)
    u32 hw = (u32)f2bf(hn);
    u32 nb = __shfl_down(hw, 1);
    if (!(gu & 1)) {
      u32* dst = (u32*)(hbuf + (size_t)((t + 1) & 1) * (B_ * D_) + hoff);
      __hip_atomic_store(dst, hw | (nb << 16), __ATOMIC_RELAXED, __HIP_MEMORY_SCOPE_AGENT);
    }
    if (t == T_ - 1) h_last[hoff] = hn;
    // drain all waves' stores, then publish the flag
    __syncthreads();
    if (tid == 0)
      __hip_atomic_store(flags + (size_t)wg * 16, (u32)(t + 1),
                         __ATOMIC_RELAXED, __HIP_MEMORY_SCOPE_AGENT);
  }
}

// ---------------- LN2: out = LN(xn + h_last) fp32 ----------------
__global__ __launch_bounds__(256) void ln2_kernel(const u16* __restrict__ xn,
    const float* __restrict__ h_last, const float* __restrict__ gam,
    const float* __restrict__ bet, float* __restrict__ out) {
  int row = blockIdx.x; int tid = threadIdx.x;
  int bi = row >> 9;
  ushort4v xv = *(const ushort4v*)(xn + (size_t)row * D_ + tid * 4);
  float4 hv = *(const float4*)(h_last + (size_t)bi * D_ + tid * 4);
  float s0 = bf2f(xv.x) + hv.x;
  float s1 = bf2f(xv.y) + hv.y;
  float s2 = bf2f(xv.z) + hv.z;
  float s3 = bf2f(xv.w) + hv.w;
  float s = s0 + s1 + s2 + s3;
  float ss = s0*s0 + s1*s1 + s2*s2 + s3*s3;
  #pragma unroll
  for (int o = 32; o > 0; o >>= 1) { s += __shfl_down(s, o); ss += __shfl_down(ss, o); }
  __shared__ float red[8];
  int w = tid >> 6, l = tid & 63;
  if (l == 0) { red[w] = s; red[4 + w] = ss; }
  __syncthreads();
  s  = red[0] + red[1] + red[2] + red[3];
  ss = red[4] + red[5] + red[6] + red[7];
  float mean = s * (1.f / D_);
  float var  = ss * (1.f / D_) - mean * mean;
  float rstd = rsqrtf(var + 1e-3f);
  float4 g = *(const float4*)(gam + tid * 4);
  float4 b = *(const float4*)(bet + tid * 4);
  float4 o4;
  o4.x = (s0 - mean) * rstd * g.x + b.x;
  o4.y = (s1 - mean) * rstd * g.y + b.y;
  o4.z = (s2 - mean) * rstd * g.z + b.z;
  o4.w = (s3 - mean) * rstd * g.w + b.w;
  *(float4*)(out + (size_t)row * D_ + tid * 4) = o4;
}

extern "C" void kernel_launch(void* const* d_in, const int* in_sizes, int n_in,
                              void* d_out, int out_size, void* d_ws, size_t ws_size,
                              hipStream_t stream) {
  const float* x    = (const float*)d_in[0];
  const float* g1   = (const float*)d_in[1];
  const float* b1   = (const float*)d_in[2];
  const float* Wk   = (const float*)d_in[3];
  const float* Wr   = (const float*)d_in[4];
  const float* bias = (const float*)d_in[5];
  const float* g2   = (const float*)d_in[6];
  const float* b2   = (const float*)d_in[7];
  char* ws = (char*)d_ws;
  u16* xn    = (u16*)(ws + OFF_XN);
  u16* Zx    = (u16*)(ws + OFF_ZX);
  u16* KT    = (u16*)(ws + OFF_KT);
  u16* RT    = (u16*)(ws + OFF_RT);
  u16* hbuf  = (u16*)(ws + OFF_HB);
  u32* flg   = (u32*)(ws + OFF_FLG);
  float* hl  = (float*)(ws + OFF_KT);    // aliases KT (dead after gemm_xk)
  float* out = (float*)d_out;

  init_kernel<<<128, 256, 0, stream>>>((u32*)hbuf, flg);
  ln1_kernel<<<B_ * T_, 256, 0, stream>>>(x, g1, b1, xn);
  transpose_bf16<<<dim3(128, 32), dim3(32, 8), 0, stream>>>(Wk, KT);
  transpose_bf16<<<dim3(128, 32), dim3(32, 8), 0, stream>>>(Wr, RT);
  gemm_xk<<<4096, 256, 0, stream>>>(xn, KT, bias, Zx);
  lstm_scan<<<32, 1024, 0, stream>>>(Zx, RT, hbuf, hl, flg);
  ln2_kernel<<<B_ * T_, 256, 0, stream>>>(xn, hl, g2, b2, out);
}

// Round 7
// 2311.599 us; speedup vs baseline: 2.5268x; 1.0029x over previous
//
#include <hip/hip_runtime.h>

typedef unsigned short u16;
typedef unsigned int   u32;
typedef unsigned long long u64;
typedef __attribute__((ext_vector_type(8)))  short  short8v;   // 8 x bf16 (as i16)
typedef __attribute__((ext_vector_type(4)))  float  f32x4;
typedef __attribute__((ext_vector_type(16))) float  f32x16;
typedef __attribute__((ext_vector_type(4)))  unsigned short ushort4v;
typedef __attribute__((ext_vector_type(4)))  u32 u32x4;

#define B_   32
#define T_   512
#define D_   1024
#define N4_  4096

// ---- workspace layout (bytes) ----
#define OFF_XN   0ull                 // xn bf16   [32*512*1024]      33554432
#define OFF_ZX   33554432ull          // Zx bf16   [512][32][1024][4] 134217728  (gate-interleaved)
#define OFF_KT   167772160ull         // kernel^T bf16 [4096][1024]    8388608  (reused as h_last after GEMM)
#define OFF_RT   176160768ull         // recurrent^T bf16 [4096][1024] 8388608
#define OFF_HB   184549376ull         // h double buffer bf16 2*[32][1024] = 131072
#define OFF_FLG  184680448ull         // flags: 32 x 64B-strided u32

__device__ inline u16 f2bf(float f) {
  union { float f; u32 u; } x; x.f = f;
  u32 r = x.u + 0x7FFFu + ((x.u >> 16) & 1u);   // RNE
  return (u16)(r >> 16);
}
__device__ inline float bf2f(u16 h) {
  union { u32 u; float f; } x; x.u = ((u32)h) << 16; return x.f;
}
__device__ inline float sigm(float x) { return 1.f / (1.f + __expf(-x)); }
__device__ inline float tanh_fast(float x) {
  float e = __expf(2.f * x);
  return 1.f - 2.f / (e + 1.f);
}

// ---------------- init: zero h buffers + flags ----------------
__global__ __launch_bounds__(256) void init_kernel(u32* hbuf, u32* flags) {
  int i = blockIdx.x * 256 + threadIdx.x;
  if (i < 32768) hbuf[i] = 0u;       // both parities: 2*32*1024 bf16 = 32768 dwords
  if (i < 32)    flags[i * 16] = 0u;
}

// ---------------- LN1: x fp32 -> xn bf16 ----------------
__global__ __launch_bounds__(256) void ln1_kernel(const float* __restrict__ x,
    const float* __restrict__ gam, const float* __restrict__ bet, u16* __restrict__ xn) {
  int row = blockIdx.x; int tid = threadIdx.x;
  const float* xr = x + (size_t)row * D_;
  float4 v = *(const float4*)(xr + tid * 4);
  float s  = v.x + v.y + v.z + v.w;
  float ss = v.x*v.x + v.y*v.y + v.z*v.z + v.w*v.w;
  #pragma unroll
  for (int o = 32; o > 0; o >>= 1) { s += __shfl_down(s, o); ss += __shfl_down(ss, o); }
  __shared__ float red[8];
  int w = tid >> 6, l = tid & 63;
  if (l == 0) { red[w] = s; red[4 + w] = ss; }
  __syncthreads();
  s  = red[0] + red[1] + red[2] + red[3];
  ss = red[4] + red[5] + red[6] + red[7];
  float mean = s * (1.f / D_);
  float var  = ss * (1.f / D_) - mean * mean;
  float rstd = rsqrtf(var + 1e-3f);
  float4 g = *(const float4*)(gam + tid * 4);
  float4 b = *(const float4*)(bet + tid * 4);
  ushort4v o4;
  o4.x = f2bf((v.x - mean) * rstd * g.x + b.x);
  o4.y = f2bf((v.y - mean) * rstd * g.y + b.y);
  o4.z = f2bf((v.z - mean) * rstd * g.z + b.z);
  o4.w = f2bf((v.w - mean) * rstd * g.w + b.w);
  *(ushort4v*)(xn + (size_t)row * D_ + tid * 4) = o4;
}

// ---------------- transpose [1024][4096] fp32 -> [4096][1024] bf16 ----------------
__global__ __launch_bounds__(256) void transpose_bf16(const float* __restrict__ W, u16* __restrict__ WT) {
  __shared__ float tile[32][33];
  int c0 = blockIdx.x * 32, r0 = blockIdx.y * 32;
  int tx = threadIdx.x, ty = threadIdx.y;
  #pragma unroll
  for (int i = ty; i < 32; i += 8)
    tile[i][tx] = W[(size_t)(r0 + i) * N4_ + c0 + tx];
  __syncthreads();
  #pragma unroll
  for (int i = ty; i < 32; i += 8)
    WT[(size_t)(c0 + i) * D_ + r0 + tx] = f2bf(tile[tx][i]);
}

// ---------------- GEMM: Zx = xn @ kernel + bias  (gate-interleaved output) ----------------
__global__ __launch_bounds__(256) void gemm_xk(const u16* __restrict__ A, const u16* __restrict__ Bt,
    const float* __restrict__ bias, u16* __restrict__ Zx) {
  __shared__ u16 As[128 * 32];
  __shared__ u16 Bs[128 * 32];
  int tid = threadIdx.x;
  int bm = blockIdx.x >> 5, bn = blockIdx.x & 31;
  int w = tid >> 6, l = tid & 63;
  int srow = tid >> 2, sk = (tid & 3) * 8;        // staging: row j*64+srow, k = sk..sk+8
  const u16* Ag = A  + (size_t)(bm * 128 + srow) * D_ + sk;
  const u16* Bg = Bt + (size_t)(bn * 128 + srow) * D_ + sk;
  int sb0 = (srow * 64 + sk * 2)          ^ ((srow & 3) << 4);
  int sb1 = ((srow + 64) * 64 + sk * 2)   ^ ((srow & 3) << 4);
  int wm = w >> 1, wn = w & 1;
  int frow = l & 15, fko = (l >> 4) * 16;         // fragment k byte offset
  f32x4 acc[4][4];
  #pragma unroll
  for (int mi = 0; mi < 4; ++mi)
    #pragma unroll
    for (int ni = 0; ni < 4; ++ni)
      #pragma unroll
      for (int j = 0; j < 4; ++j) acc[mi][ni][j] = 0.f;

  short8v ap0 = *(const short8v*)(Ag);
  short8v ap1 = *(const short8v*)(Ag + 64 * (size_t)D_);
  short8v bp0 = *(const short8v*)(Bg);
  short8v bp1 = *(const short8v*)(Bg + 64 * (size_t)D_);

  for (int kt = 0; kt < 32; ++kt) {
    __syncthreads();
    *(short8v*)((char*)As + sb0) = ap0;
    *(short8v*)((char*)As + sb1) = ap1;
    *(short8v*)((char*)Bs + sb0) = bp0;
    *(short8v*)((char*)Bs + sb1) = bp1;
    __syncthreads();
    if (kt < 31) {
      ap0 = *(const short8v*)(Ag + (kt + 1) * 32);
      ap1 = *(const short8v*)(Ag + 64 * (size_t)D_ + (kt + 1) * 32);
      bp0 = *(const short8v*)(Bg + (kt + 1) * 32);
      bp1 = *(const short8v*)(Bg + 64 * (size_t)D_ + (kt + 1) * 32);
    }
    short8v af[4], bfr[4];
    #pragma unroll
    for (int mi = 0; mi < 4; ++mi) {
      int r = wm * 64 + mi * 16 + frow;
      af[mi] = *(const short8v*)((char*)As + ((r * 64 + fko) ^ ((r & 3) << 4)));
    }
    #pragma unroll
    for (int ni = 0; ni < 4; ++ni) {
      int r = wn * 64 + ni * 16 + frow;
      bfr[ni] = *(const short8v*)((char*)Bs + ((r * 64 + fko) ^ ((r & 3) << 4)));
    }
    #pragma unroll
    for (int mi = 0; mi < 4; ++mi)
      #pragma unroll
      for (int ni = 0; ni < 4; ++ni)
        acc[mi][ni] = __builtin_amdgcn_mfma_f32_16x16x32_bf16(af[mi], bfr[ni], acc[mi][ni], 0, 0, 0);
  }
  // epilogue: +bias, bf16, remap rows to [t][b] and cols to [unit][gate]
  #pragma unroll
  for (int mi = 0; mi < 4; ++mi) {
    #pragma unroll
    for (int ni = 0; ni < 4; ++ni) {
      int col = bn * 128 + wn * 64 + ni * 16 + (l & 15);
      float bv = bias[col];
      int colp = ((col & 1023) << 2) | (col >> 10);   // gate-interleaved
      #pragma unroll
      for (int j = 0; j < 4; ++j) {
        int row = bm * 128 + wm * 64 + mi * 16 + (l >> 4) * 4 + j;
        int zrow = (row & 511) * 32 + (row >> 9);
        Zx[(size_t)zrow * N4_ + colp] = f2bf(acc[mi][ni][j] + bv);
      }
    }
  }
}

// ---------------- persistent LSTM scan ----------------
// 32 WGs x 1024 thr (16 waves = 4 K-splits x 4 gates). WG owns units [wg*32, wg*32+32).
// Exchange: wave0-only flag poll + raw s_barrier release; 16B coherent h loads.
// R-slice (256KB/WG) is re-read from L2 every step (residency unachievable at this
// occupancy) — so its 16 fragment loads are ISSUED AT THE TOP of each iteration,
// pinned by sched_barrier, to overlap the ~2us exchange window instead of
// serializing after it inside the K-loop (R6 post-mortem: that serial feed was
// ~1.7us/step of the 4.0us step time).
__global__ __launch_bounds__(1024, 4) void lstm_scan(const u16* __restrict__ Zx,
    const u16* __restrict__ RT, u16* hbuf, float* h_last, u32* flags) {
  __shared__ u16   h_lds[B_ * D_];           // 64 KB, XOR-swizzled rows
  __shared__ float z_lds[128 * 136];         // 69.6 KB: [ks*32+row][stride 136]
  int tid = threadIdx.x;
  int wg = blockIdx.x;
  int w = tid >> 6, l = tid & 63;
  int ks = w >> 2, cg = w & 3;               // K-range ks*256..+256, gate cg

  // per-lane R^T fragment base (16 x 16B per step)
  const u16* Rp = RT + (size_t)(cg * 1024 + wg * 32 + (l & 31)) * D_
                + ks * 256 + (l >> 5) * 8;

  // A-fragment addressing (h in LDS, swizzled)
  int arow = l & 31;
  int abase = arow * 2048 + (ks * 256 + (l >> 5) * 8) * 2;
  int asw = (arow & 7) << 4;
  // gate cell: (grow, gu)
  int grow = tid >> 5, gu = tid & 31;
  const u16* zx_p = Zx + (size_t)grow * N4_ + (wg * 32 + gu) * 4;
  int hoff = grow * D_ + wg * 32 + gu;
  float c = 0.f;
  const u32* fp = flags + (size_t)(l & 31) * 16;

  #pragma unroll 1
  for (int t = 0; t < T_; ++t) {
    // (1) issue this step's R-fragment loads NOW — they complete under the exchange
    short8v bfrag[16];
    #pragma unroll
    for (int kt = 0; kt < 16; ++kt) bfrag[kt] = *(const short8v*)(Rp + kt * 16);
    // (2) Zx prefetch (4 gate pre-activations, one 8B load)
    u64 zq = *(const u64*)(zx_p + (size_t)t * B_ * N4_);
    __builtin_amdgcn_sched_barrier(0);   // nothing above sinks below (loads stay issued)

    // (3) wave0 polls the 32 per-WG flags; raw s_barrier releases the other 15 waves
    if (w == 0) {
      while (true) {
        u32 f = __hip_atomic_load(fp, __ATOMIC_RELAXED, __HIP_MEMORY_SCOPE_AGENT);
        if (__all((int)(f >= (u32)t))) break;
      }
    }
    __builtin_amdgcn_s_barrier();
    __builtin_amdgcn_sched_barrier(0);

    // (4) bulk-load h: 4 x 16B coherent loads per thread (sc0 sc1 bypass stale L1/L2)
    const char* hbp = (const char*)hbuf + (size_t)(t & 1) * 65536;
    u32x4 hv[4];
    #pragma unroll
    for (int j = 0; j < 4; ++j) {
      const char* p = hbp + j * 16384 + tid * 16;
      asm volatile("global_load_dwordx4 %0, %1, off sc0 sc1"
                   : "=&v"(hv[j]) : "v"(p) : "memory");
    }
    asm volatile("s_waitcnt vmcnt(0)" ::: "memory");   // drains h + R + Zx loads
    __builtin_amdgcn_sched_barrier(0);
    #pragma unroll
    for (int j = 0; j < 4; ++j) {
      int byte = j * 16384 + tid * 16;
      int row = byte >> 11;
      *(u32x4*)((char*)h_lds + (byte ^ ((row & 7) << 4))) = hv[j];
    }
    __syncthreads();

    // (5) K-loop: 16 x (ds_read_b128 + mfma 32x32x16), B operands already in registers
    f32x16 acc;
    #pragma unroll
    for (int i = 0; i < 16; ++i) acc[i] = 0.f;
    #pragma unroll
    for (int kt = 0; kt < 16; ++kt) {
      short8v a = *(const short8v*)((const char*)h_lds + ((abase + kt * 32) ^ asw));
      acc = __builtin_amdgcn_mfma_f32_32x32x16_bf16(a, bfrag[kt], acc, 0, 0, 0);
    }
    // write K-partials: D layout row=(r&3)+8*(r>>2)+4*(lane>>5), col=lane&31
    #pragma unroll
    for (int r = 0; r < 16; ++r) {
      int rowD = (r & 3) + 8 * (r >> 2) + 4 * (l >> 5);
      z_lds[(ks * 32 + rowD) * 136 + cg * 32 + (l & 31)] = acc[r];
    }
    __syncthreads();

    // (6) gates: one cell per thread
    float z0 = bf2f((u16)(zq        & 0xFFFFu));
    float z1 = bf2f((u16)((zq >> 16) & 0xFFFFu));
    float z2 = bf2f((u16)((zq >> 32) & 0xFFFFu));
    float z3 = bf2f((u16)((zq >> 48) & 0xFFFFu));
    #pragma unroll
    for (int kss = 0; kss < 4; ++kss) {
      const float* zr = &z_lds[(kss * 32 + grow) * 136 + gu];
      z0 += zr[0]; z1 += zr[32]; z2 += zr[64]; z3 += zr[96];
    }
    float cn = sigm(z1) * c + sigm(z0) * tanh_fast(z2);
    float hn = sigm(z3) * tanh_fast(cn);
    c = cn;

    // (7) publish h (pair lanes -> u32 agent-scope store)
    u32 hw = (u32)f2bf(hn);
    u32 nb = __shfl_down(hw, 1);
    if (!(gu & 1)) {
      u32* dst = (u32*)(hbuf + (size_t)((t + 1) & 1) * (B_ * D_) + hoff);
      __hip_atomic_store(dst, hw | (nb << 16), __ATOMIC_RELAXED, __HIP_MEMORY_SCOPE_AGENT);
    }
    if (t == T_ - 1) h_last[hoff] = hn;
    // drain all waves' stores, then publish the flag
    __syncthreads();
    if (tid == 0)
      __hip_atomic_store(flags + (size_t)wg * 16, (u32)(t + 1),
                         __ATOMIC_RELAXED, __HIP_MEMORY_SCOPE_AGENT);
  }
}

// ---------------- LN2: out = LN(xn + h_last) fp32 ----------------
__global__ __launch_bounds__(256) void ln2_kernel(const u16* __restrict__ xn,
    const float* __restrict__ h_last, const float* __restrict__ gam,
    const float* __restrict__ bet, float* __restrict__ out) {
  int row = blockIdx.x; int tid = threadIdx.x;
  int bi = row >> 9;
  ushort4v xv = *(const ushort4v*)(xn + (size_t)row * D_ + tid * 4);
  float4 hv = *(const float4*)(h_last + (size_t)bi * D_ + tid * 4);
  float s0 = bf2f(xv.x) + hv.x;
  float s1 = bf2f(xv.y) + hv.y;
  float s2 = bf2f(xv.z) + hv.z;
  float s3 = bf2f(xv.w) + hv.w;
  float s = s0 + s1 + s2 + s3;
  float ss = s0*s0 + s1*s1 + s2*s2 + s3*s3;
  #pragma unroll
  for (int o = 32; o > 0; o >>= 1) { s += __shfl_down(s, o); ss += __shfl_down(ss, o); }
  __shared__ float red[8];
  int w = tid >> 6, l = tid & 63;
  if (l == 0) { red[w] = s; red[4 + w] = ss; }
  __syncthreads();
  s  = red[0] + red[1] + red[2] + red[3];
  ss = red[4] + red[5] + red[6] + red[7];
  float mean = s * (1.f / D_);
  float var  = ss * (1.f / D_) - mean * mean;
  float rstd = rsqrtf(var + 1e-3f);
  float4 g = *(const float4*)(gam + tid * 4);
  float4 b = *(const float4*)(bet + tid * 4);
  float4 o4;
  o4.x = (s0 - mean) * rstd * g.x + b.x;
  o4.y = (s1 - mean) * rstd * g.y + b.y;
  o4.z = (s2 - mean) * rstd * g.z + b.z;
  o4.w = (s3 - mean) * rstd * g.w + b.w;
  *(float4*)(out + (size_t)row * D_ + tid * 4) = o4;
}

extern "C" void kernel_launch(void* const* d_in, const int* in_sizes, int n_in,
                              void* d_out, int out_size, void* d_ws, size_t ws_size,
                              hipStream_t stream) {
  const float* x    = (const float*)d_in[0];
  const float* g1   = (const float*)d_in[1];
  const float* b1   = (const float*)d_in[2];
  const float* Wk   = (const float*)d_in[3];
  const float* Wr   = (const float*)d_in[4];
  const float* bias = (const float*)d_in[5];
  const float* g2   = (const float*)d_in[6];
  const float* b2   = (const float*)d_in[7];
  char* ws = (char*)d_ws;
  u16* xn    = (u16*)(ws + OFF_XN);
  u16* Zx    = (u16*)(ws + OFF_ZX);
  u16* KT    = (u16*)(ws + OFF_KT);
  u16* RT    = (u16*)(ws + OFF_RT);
  u16* hbuf  = (u16*)(ws + OFF_HB);
  u32* flg   = (u32*)(ws + OFF_FLG);
  float* hl  = (float*)(ws + OFF_KT);    // aliases KT (dead after gemm_xk)
  float* out = (float*)d_out;

  init_kernel<<<128, 256, 0, stream>>>((u32*)hbuf, flg);
  ln1_kernel<<<B_ * T_, 256, 0, stream>>>(x, g1, b1, xn);
  transpose_bf16<<<dim3(128, 32), dim3(32, 8), 0, stream>>>(Wk, KT);
  transpose_bf16<<<dim3(128, 32), dim3(32, 8), 0, stream>>>(Wr, RT);
  gemm_xk<<<4096, 256, 0, stream>>>(xn, KT, bias, Zx);
  lstm_scan<<<32, 1024, 0, stream>>>(Zx, RT, hbuf, hl, flg);
  ln2_kernel<<<B_ * T_, 256, 0, stream>>>(xn, hl, g2, b2, out);
}